// Round 15
// baseline (102.531 us; speedup 1.0000x reference)
//
#include <hip/hip_runtime.h>

constexpr int W    = 96;
constexpr int NPIX = 9216;
constexpr int NM   = 31;     // Fourier modes; tail < 5e-8 per kernel value
constexpr int NPKB = 16;     // 64 channels = DC + 31 cos + 31 sin + pad
constexpr int NP   = 17;     // + sxy=3 gaussian "pack"

constexpr float LCLIP = 18.420681f;   // -log(1e-8)
constexpr float K512  = 0.0122718463f; // 2*pi/512

// ---- k_H: (iter0: basis gen) + q-recon + splat + horizontal conv ----
// block = 8 rows x pack, TB=192, 4 outputs/thread (x, x+24, x+48, x+72).
// MODE 0: q0 from mask; computes basis in-register (writes B4, planes 0..15);
//         grid-y doubled, g0>=NP -> ones pipeline (for ksum).
// MODE 1: recon q from partV; reduce partVk -> persist ksum. MODE 2: read ksum.
template<int MODE>
__global__ __launch_bounds__(192) void k_H(const float* __restrict__ img,
        const int* __restrict__ mask, float4* __restrict__ B4,
        const float* __restrict__ partV, const float* __restrict__ partVk,
        float* __restrict__ ksum, const float* __restrict__ qprev, float* __restrict__ qcur,
        float4* __restrict__ H4T, float* __restrict__ H3T,
        float4* __restrict__ H4Tk, float* __restrict__ H3Tk)
{
    __shared__ float4 P4[8*97];        // padded rows -> rows on distinct bank groups
    __shared__ float  qp[8*97];        // g3 pack only
    __shared__ float  tw[193];
    const int  t    = threadIdx.x;
    const int  B    = blockIdx.x;
    const int  g0   = blockIdx.y;
    const bool ones = (MODE==0) && (g0 >= NP);
    const int  pack = ones ? g0 - NP : g0;
    const bool G3   = (pack == NPKB);

    if (t < 193){
        float d = (float)(t - 96);
        tw[t] = G3 ? __expf(-d*d*(1.f/18.f)) : __expf(-d*d*(1.f/5000.f));
    }
    float A[4];
    if (!G3){
        #pragma unroll
        for (int jj = 0; jj < 4; ++jj){
            int ch = 4*pack + jj;
            if (ch == 0)       A[jj] = 0.6923648f;                // 10*sqrt(400*pi)/512
            else if (ch <= 62){
                int m = (ch <= NM) ? ch : ch - NM;
                A[jj] = 1.3847296f * __expf(-0.0150598f*(float)(m*m));
            } else             A[jj] = 0.f;
        }
    }

    // ---- staging: 4 px/thread (recon q, [iter0: basis], splat) ----
    #pragma unroll
    for (int k = 0; k < 4; ++k){
        int l  = t + k*192;
        int px = B*768 + l;
        float q;
        if (ones){
            q = 1.f;
        } else if (MODE == 0){
            q = (mask[px]==0) ? 1.f/(1.f+__expf( LCLIP)) : 1.f/(1.f+__expf(-LCLIP));
        } else {
            float m = 0.f;
            #pragma unroll
            for (int p = 0; p < NP; ++p) m += partV[(size_t)p*NPIX + px];
            float kk;
            if (MODE == 1){
                kk = 0.f;
                #pragma unroll
                for (int p = 0; p < NP; ++p) kk += partVk[(size_t)p*NPIX + px];
                kk -= 13.f;                          // remove diagonal from colsum
                if (g0 == 0) ksum[px] = kk;          // persist (iteration-invariant)
            } else {
                kk = ksum[px];
            }
            float duv = (mask[px]==0) ? LCLIP : -LCLIP;
            float delta = duv + kk - 2.f*(m - 13.f*qprev[px]);   // diag removal
            q = 1.f/(1.f+__expf(delta));
        }
        if (!ones && g0 == 0) qcur[px] = q;          // designated writer
        int ryl = l/96, xx = l - ryl*96;
        if (!G3){
            float cv0, cv1, cv2, cv3;
            if (MODE == 0){
                // basis via 1 sincos + angle-addition recurrence (depth <= 31)
                float cv[4];
                #pragma unroll
                for (int jj = 0; jj < 4; ++jj) cv[jj] = (4*pack+jj == 0) ? 1.f : 0.f;
                float s1, c1;
                sincosf(img[px]*K512, &s1, &c1);
                float cm = 1.f, sm = 0.f;
                for (int m = 1; m <= NM; ++m){
                    float cn = cm*c1 - sm*s1;
                    float sn = sm*c1 + cm*s1;
                    cm = cn; sm = sn;
                    #pragma unroll
                    for (int jj = 0; jj < 4; ++jj){
                        int ch = 4*pack + jj;
                        int mm = (ch <= NM) ? ch : ch - NM;
                        if (ch >= 1 && ch <= 62 && mm == m) cv[jj] = (ch <= NM) ? cm : sm;
                    }
                }
                cv0=cv[0]; cv1=cv[1]; cv2=cv[2]; cv3=cv[3];
                if (!ones) B4[(size_t)pack*NPIX + px] = make_float4(cv0,cv1,cv2,cv3);
            } else {
                float4 b = B4[(size_t)pack*NPIX + px];
                cv0=b.x; cv1=b.y; cv2=b.z; cv3=b.w;
            }
            P4[ryl*97 + xx] = make_float4(q*A[0]*cv0, q*A[1]*cv1, q*A[2]*cv2, q*A[3]*cv3);
        } else {
            qp[ryl*97 + xx] = q;
        }
    }
    __syncthreads();

    // ---- H-conv: thread (r = t&7, xg = t>>3) owns x in {xg, xg+24, xg+48, xg+72} ----
    const int r = t & 7, xg = t >> 3;
    const int y = 8*B + r;
    if (!G3){
        float4 a0 = make_float4(0.f,0.f,0.f,0.f), a1 = a0, a2 = a0, a3 = a0;
        #pragma unroll 4
        for (int xp = 0; xp < W; ++xp){
            float4 v  = P4[r*97 + xp];               // bank-spread broadcast
            int    i0 = xg - xp + 96;
            float  w0 = tw[i0],      w1 = tw[i0+24]; // ds_read2 pairs
            float  w2 = tw[i0+48],   w3 = tw[i0+72];
            a0.x = fmaf(w0,v.x,a0.x); a0.y = fmaf(w0,v.y,a0.y);
            a0.z = fmaf(w0,v.z,a0.z); a0.w = fmaf(w0,v.w,a0.w);
            a1.x = fmaf(w1,v.x,a1.x); a1.y = fmaf(w1,v.y,a1.y);
            a1.z = fmaf(w1,v.z,a1.z); a1.w = fmaf(w1,v.w,a1.w);
            a2.x = fmaf(w2,v.x,a2.x); a2.y = fmaf(w2,v.y,a2.y);
            a2.z = fmaf(w2,v.z,a2.z); a2.w = fmaf(w2,v.w,a2.w);
            a3.x = fmaf(w3,v.x,a3.x); a3.y = fmaf(w3,v.y,a3.y);
            a3.z = fmaf(w3,v.z,a3.z); a3.w = fmaf(w3,v.w,a3.w);
        }
        float4* dst = (ones ? H4Tk : H4T) + (size_t)pack*NPIX + y;
        dst[(xg     )*W] = a0;                       // transposed stores
        dst[(xg + 24)*W] = a1;
        dst[(xg + 48)*W] = a2;
        dst[(xg + 72)*W] = a3;
    } else {
        float h0=0.f, h1=0.f, h2=0.f, h3=0.f;
        #pragma unroll 4
        for (int xp = 0; xp < W; ++xp){
            float qv = qp[r*97 + xp];
            int   i0 = xg - xp + 96;
            h0 = fmaf(tw[i0],    qv, h0);
            h1 = fmaf(tw[i0+24], qv, h1);
            h2 = fmaf(tw[i0+48], qv, h2);
            h3 = fmaf(tw[i0+72], qv, h3);
        }
        float* dg = (ones ? H3Tk : H3T) + y;
        dg[(xg     )*W] = h0;
        dg[(xg + 24)*W] = h1;
        dg[(xg + 48)*W] = h2;
        dg[(xg + 72)*W] = h3;
    }
}

// ---- k_V: vertical conv + slice. block = 8 cols x pack, TB=192, 4 outputs/thread ----
__global__ __launch_bounds__(192) void k_V(const float4* __restrict__ B4,
        const float4* __restrict__ H4T, const float4* __restrict__ H4Tk,
        const float* __restrict__ H3T, const float* __restrict__ H3Tk,
        float* __restrict__ partV, float* __restrict__ partVk)
{
    __shared__ float4 Hl[8*97];
    __shared__ float  Hl3[8*97];
    __shared__ float  tw[193];
    const int  t    = threadIdx.x;
    const int  C    = blockIdx.x;
    const int  g0   = blockIdx.y;
    const bool ones = g0 >= NP;
    const int  pack = ones ? g0 - NP : g0;
    const bool G3   = (pack == NPKB);

    if (t < 193){
        float d = (float)(t - 96);
        tw[t] = G3 ? __expf(-d*d*(1.f/18.f)) : __expf(-d*d*(1.f/5000.f));
    }
    // stage 8 H-columns (coalesced: yy fastest)
    #pragma unroll
    for (int k = 0; k < 4; ++k){
        int l = t + k*192;
        int col = l/96, yy = l - col*96;
        if (!G3) Hl[col*97 + yy]  = (ones ? H4Tk : H4T)[(size_t)pack*NPIX + (8*C+col)*W + yy];
        else     Hl3[col*97 + yy] = (ones ? H3Tk : H3T)[(8*C+col)*W + yy];
    }
    __syncthreads();

    const int r = t & 7, yg = t >> 3;            // col r, outputs yo in {yg,+24,+48,+72}
    const int x = 8*C + r;
    if (!G3){
        float4 a0 = make_float4(0.f,0.f,0.f,0.f), a1 = a0, a2 = a0, a3 = a0;
        #pragma unroll 4
        for (int yp = 0; yp < W; ++yp){
            float4 v  = Hl[r*97 + yp];
            int    i0 = yg - yp + 96;
            float  w0 = tw[i0],    w1 = tw[i0+24];
            float  w2 = tw[i0+48], w3 = tw[i0+72];
            a0.x = fmaf(w0,v.x,a0.x); a0.y = fmaf(w0,v.y,a0.y);
            a0.z = fmaf(w0,v.z,a0.z); a0.w = fmaf(w0,v.w,a0.w);
            a1.x = fmaf(w1,v.x,a1.x); a1.y = fmaf(w1,v.y,a1.y);
            a1.z = fmaf(w1,v.z,a1.z); a1.w = fmaf(w1,v.w,a1.w);
            a2.x = fmaf(w2,v.x,a2.x); a2.y = fmaf(w2,v.y,a2.y);
            a2.z = fmaf(w2,v.z,a2.z); a2.w = fmaf(w2,v.w,a2.w);
            a3.x = fmaf(w3,v.x,a3.x); a3.y = fmaf(w3,v.y,a3.y);
            a3.z = fmaf(w3,v.z,a3.z); a3.w = fmaf(w3,v.w,a3.w);
        }
        float* dst = ones ? partVk : partV;
        #pragma unroll
        for (int o = 0; o < 4; ++o){
            float4 a = (o==0)?a0:(o==1)?a1:(o==2)?a2:a3;
            int px = (yg + 24*o)*W + x;
            float4 b = B4[(size_t)pack*NPIX + px];   // slice basis at output pixel
            dst[(size_t)pack*NPIX + px] = a.x*b.x + a.y*b.y + a.z*b.z + a.w*b.w;
        }
    } else {
        float h0=0.f, h1=0.f, h2=0.f, h3=0.f;
        #pragma unroll 4
        for (int yp = 0; yp < W; ++yp){
            float v = Hl3[r*97 + yp];
            int  i0 = yg - yp + 96;
            h0 = fmaf(tw[i0],    v, h0);
            h1 = fmaf(tw[i0+24], v, h1);
            h2 = fmaf(tw[i0+48], v, h2);
            h3 = fmaf(tw[i0+72], v, h3);
        }
        float* dst = (ones ? partVk : partV) + (size_t)pack*NPIX + x;
        dst[(yg     )*W] = 3.f*h0;                   // gaussian compat
        dst[(yg + 24)*W] = 3.f*h1;
        dst[(yg + 48)*W] = 3.f*h2;
        dst[(yg + 72)*W] = 3.f*h3;
    }
}

// ---- final: 5th update + argmax ----
__global__ __launch_bounds__(256) void k_F(const int* __restrict__ mask,
        const float* __restrict__ partV, const float* __restrict__ ksum,
        const float* __restrict__ qprev, float* __restrict__ out){
    int px = blockIdx.x*256 + threadIdx.x;
    float m = 0.f;
    #pragma unroll
    for (int p = 0; p < NP; ++p) m += partV[(size_t)p*NPIX + px];
    float duv = (mask[px]==0) ? LCLIP : -LCLIP;
    float delta = duv + ksum[px] - 2.f*(m - 13.f*qprev[px]);
    out[px] = (delta > 0.f) ? 1.f : 0.f;             // argmax; tie -> label 0
}

extern "C" void kernel_launch(void* const* d_in, const int* in_sizes, int n_in,
                              void* d_out, int out_size, void* d_ws, size_t ws_size,
                              hipStream_t stream){
    const float* img  = (const float*)d_in[0];
    const int*   mask = (const int*)d_in[1];
    float* out = (float*)d_out;
    float* ws  = (float*)d_ws;

    constexpr size_t TBL = (size_t)NPKB*NPIX*4;      // floats in a pack table
    float4* B4    = (float4*)ws;
    float4* H4T   = (float4*)(ws + TBL);
    float4* H4Tk  = (float4*)(ws + 2*TBL);
    float*  base  = ws + 3*TBL;
    float* H3T   = base;
    float* H3Tk  = H3T  + NPIX;
    float* partV = H3Tk + NPIX;                      // [17][NPIX]
    float* partVk= partV + (size_t)NP*NPIX;
    float* qA    = partVk + (size_t)NP*NPIX;
    float* qB    = qA + NPIX;
    float* ksum  = qB + NPIX;

    dim3 b(192);
    // iter 0: q0 (+ ones pipeline for ksum); basis computed in-register, B4 persisted
    k_H<0><<<dim3(12,2*NP), b, 0, stream>>>(img, mask, B4, partV, partVk, ksum, qA, qA, H4T, H3T, H4Tk, H3Tk);
    k_V   <<<dim3(12,2*NP), b, 0, stream>>>(B4, H4T, H4Tk, H3T, H3Tk, partV, partVk);
    // iter 1: recon q1, persist ksum
    k_H<1><<<dim3(12,NP), b, 0, stream>>>(img, mask, B4, partV, partVk, ksum, qA, qB, H4T, H3T, H4Tk, H3Tk);
    k_V   <<<dim3(12,NP), b, 0, stream>>>(B4, H4T, H4Tk, H3T, H3Tk, partV, partVk);
    // iters 2..4
    k_H<2><<<dim3(12,NP), b, 0, stream>>>(img, mask, B4, partV, partVk, ksum, qB, qA, H4T, H3T, H4Tk, H3Tk);
    k_V   <<<dim3(12,NP), b, 0, stream>>>(B4, H4T, H4Tk, H3T, H3Tk, partV, partVk);
    k_H<2><<<dim3(12,NP), b, 0, stream>>>(img, mask, B4, partV, partVk, ksum, qA, qB, H4T, H3T, H4Tk, H3Tk);
    k_V   <<<dim3(12,NP), b, 0, stream>>>(B4, H4T, H4Tk, H3T, H3Tk, partV, partVk);
    k_H<2><<<dim3(12,NP), b, 0, stream>>>(img, mask, B4, partV, partVk, ksum, qB, qA, H4T, H3T, H4Tk, H3Tk);
    k_V   <<<dim3(12,NP), b, 0, stream>>>(B4, H4T, H4Tk, H3T, H3Tk, partV, partVk);
    // iter 5: final update + argmax (qprev = q4 = qA)
    k_F<<<dim3(36), dim3(256), 0, stream>>>(mask, partV, ksum, qA, out);
}

// Round 16
// 76.469 us; speedup vs baseline: 1.3408x; 1.3408x over previous
//
#include <hip/hip_runtime.h>

constexpr int W    = 96;
constexpr int NPIX = 9216;
constexpr int NM   = 23;     // Fourier modes @ period 360; truncation ~1e-7/value
constexpr int NPKB = 12;     // 48 channels = DC + 23 cos + 23 sin + pad
constexpr int NP   = 13;     // + sxy=3 gaussian "pack"

constexpr float LCLIP = 18.420681f;    // -log(1e-8)
constexpr float KTH   = 0.0174532925f; // 2*pi/360 (period 360: alias e^-27.6 ~ 1e-12)
constexpr float ACOEF = 1.9693944f;    // 10 * 2*sqrt(400*pi)/360
constexpr float ADC   = 0.9846972f;    // half weight for DC
constexpr float AEXP  = 0.0304617f;    // 100*(2*pi/360)^2

// ---- init: Fourier basis via 1 sincos + angle-addition recurrence ----
__global__ __launch_bounds__(256) void k_init(const float* __restrict__ img,
                                              float4* __restrict__ B4){
    int px = blockIdx.x*256 + threadIdx.x;
    float th = img[px] * KTH;
    float c[48];
    c[0] = 1.f; c[47] = 0.f;
    float s1, c1;
    sincosf(th, &s1, &c1);                     // libm: accurate reduction
    float cm = 1.f, sm = 0.f;
    #pragma unroll
    for (int m = 1; m <= NM; ++m){
        float cn = cm*c1 - sm*s1;              // angle addition: err ~ sqrt(m)*eps
        float sn = sm*c1 + cm*s1;
        cm = cn; sm = sn;
        c[m]    = cm;                          // cos channels 1..23
        c[NM+m] = sm;                          // sin channels 24..46
    }
    #pragma unroll
    for (int p = 0; p < NPKB; ++p)
        B4[(size_t)p*NPIX + px] = make_float4(c[4*p], c[4*p+1], c[4*p+2], c[4*p+3]);
}

// ---- k_H: q-recon + splat + horizontal conv. block = 8 rows x pack, 2 outputs/thread ----
// MODE 0: q0 from mask; grid-y doubled, g0>=NP -> ones pipeline (for ksum).
// MODE 1: recon q from partV; reduce partVk -> persist ksum. MODE 2: recon q; read ksum.
template<int MODE>
__global__ __launch_bounds__(384) void k_H(const int* __restrict__ mask,
        const float4* __restrict__ B4,
        const float* __restrict__ partV, const float* __restrict__ partVk,
        float* __restrict__ ksum, const float* __restrict__ qprev, float* __restrict__ qcur,
        float4* __restrict__ H4T, float* __restrict__ H3T,
        float4* __restrict__ H4Tk, float* __restrict__ H3Tk)
{
    __shared__ float4 P4[8*97];        // padded rows: rows land on distinct bank groups
    __shared__ float  qp[8*97];        // g3 pack only
    __shared__ float  tw[193];
    const int  t    = threadIdx.x;
    const int  B    = blockIdx.x;
    const int  g0   = blockIdx.y;
    const bool ones = (MODE==0) && (g0 >= NP);
    const int  pack = ones ? g0 - NP : g0;
    const bool G3   = (pack == NPKB);

    if (t < 193){
        float d = (float)(t - 96);
        tw[t] = G3 ? __expf(-d*d*(1.f/18.f)) : __expf(-d*d*(1.f/5000.f));
    }
    float A[4];
    if (!G3){
        #pragma unroll
        for (int jj = 0; jj < 4; ++jj){
            int ch = 4*pack + jj;
            if (ch == 0)       A[jj] = ADC;
            else if (ch <= 46){
                int m = (ch <= NM) ? ch : ch - NM;
                A[jj] = ACOEF * __expf(-AEXP*(float)(m*m));
            } else             A[jj] = 0.f;
        }
    }

    // ---- recon q + splat (2 px/thread, coalesced) ----
    #pragma unroll
    for (int k = 0; k < 2; ++k){
        int l  = t + k*384;
        int px = B*768 + l;
        float q;
        if (ones){
            q = 1.f;
        } else if (MODE == 0){
            q = (mask[px]==0) ? 1.f/(1.f+__expf( LCLIP)) : 1.f/(1.f+__expf(-LCLIP));
        } else {
            float m = 0.f;
            #pragma unroll
            for (int p = 0; p < NP; ++p) m += partV[(size_t)p*NPIX + px];
            float kk;
            if (MODE == 1){
                kk = 0.f;
                #pragma unroll
                for (int p = 0; p < NP; ++p) kk += partVk[(size_t)p*NPIX + px];
                kk -= 13.f;                          // remove diagonal from colsum
                if (g0 == 0) ksum[px] = kk;          // persist (iteration-invariant)
            } else {
                kk = ksum[px];
            }
            float duv = (mask[px]==0) ? LCLIP : -LCLIP;
            float delta = duv + kk - 2.f*(m - 13.f*qprev[px]);   // diag removal
            q = 1.f/(1.f+__expf(delta));
        }
        if (!ones && g0 == 0) qcur[px] = q;          // designated writer
        int ryl = l/96, xx = l - ryl*96;
        if (!G3){
            float4 b = B4[(size_t)pack*NPIX + px];
            P4[ryl*97 + xx] = make_float4(q*A[0]*b.x, q*A[1]*b.y, q*A[2]*b.z, q*A[3]*b.w);
        } else {
            qp[ryl*97 + xx] = q;
        }
    }
    __syncthreads();

    // ---- H-conv: thread (r = t&7, xg = t>>3) owns outputs x = xg, xg+48 of row y ----
    const int r = t & 7, xg = t >> 3;
    const int y = 8*B + r;
    if (!G3){
        float4 a0 = make_float4(0.f,0.f,0.f,0.f), a1 = a0;
        #pragma unroll 4
        for (int xp = 0; xp < W; ++xp){
            float4 v  = P4[r*97 + xp];               // 8 bank-spread broadcasts
            float  w0 = tw[xg - xp + 96];            // ds_read2_b32 pair
            float  w1 = tw[xg - xp + 96 + 48];
            a0.x = fmaf(w0,v.x,a0.x); a0.y = fmaf(w0,v.y,a0.y);
            a0.z = fmaf(w0,v.z,a0.z); a0.w = fmaf(w0,v.w,a0.w);
            a1.x = fmaf(w1,v.x,a1.x); a1.y = fmaf(w1,v.y,a1.y);
            a1.z = fmaf(w1,v.z,a1.z); a1.w = fmaf(w1,v.w,a1.w);
        }
        float4* dst = ones ? H4Tk : H4T;
        dst[(size_t)pack*NPIX + xg*W      + y] = a0; // transposed store, 8-lane chunks
        dst[(size_t)pack*NPIX + (xg+48)*W + y] = a1;
    } else {
        float h0 = 0.f, h1 = 0.f;
        #pragma unroll 4
        for (int xp = 0; xp < W; ++xp){
            float qv = qp[r*97 + xp];
            h0 = fmaf(tw[xg - xp + 96],      qv, h0);
            h1 = fmaf(tw[xg - xp + 96 + 48], qv, h1);
        }
        float* dg = ones ? H3Tk : H3T;
        dg[xg*W + y] = h0; dg[(xg+48)*W + y] = h1;
    }
}

// ---- k_V: vertical conv + slice. block = 8 cols x pack, 2 outputs/thread ----
__global__ __launch_bounds__(384) void k_V(const float4* __restrict__ B4,
        const float4* __restrict__ H4T, const float4* __restrict__ H4Tk,
        const float* __restrict__ H3T, const float* __restrict__ H3Tk,
        float* __restrict__ partV, float* __restrict__ partVk)
{
    __shared__ float4 Hl[8*97];
    __shared__ float  Hl3[8*97];
    __shared__ float  tw[193];
    const int  t    = threadIdx.x;
    const int  C    = blockIdx.x;
    const int  g0   = blockIdx.y;
    const bool ones = g0 >= NP;
    const int  pack = ones ? g0 - NP : g0;
    const bool G3   = (pack == NPKB);

    if (t < 193){
        float d = (float)(t - 96);
        tw[t] = G3 ? __expf(-d*d*(1.f/18.f)) : __expf(-d*d*(1.f/5000.f));
    }
    // stage 8 H-columns (coalesced: yy fastest)
    #pragma unroll
    for (int k = 0; k < 2; ++k){
        int l = t + k*384;
        int col = l/96, yy = l - col*96;
        if (!G3) Hl[col*97 + yy]  = (ones ? H4Tk : H4T)[(size_t)pack*NPIX + (8*C+col)*W + yy];
        else     Hl3[col*97 + yy] = (ones ? H3Tk : H3T)[(8*C+col)*W + yy];
    }
    __syncthreads();

    const int r = t & 7, yg = t >> 3;            // col r, outputs yo = yg, yg+48
    const int x = 8*C + r;
    if (!G3){
        float4 a0 = make_float4(0.f,0.f,0.f,0.f), a1 = a0;
        #pragma unroll 4
        for (int yp = 0; yp < W; ++yp){
            float4 v  = Hl[r*97 + yp];
            float  w0 = tw[yg - yp + 96];
            float  w1 = tw[yg - yp + 96 + 48];
            a0.x = fmaf(w0,v.x,a0.x); a0.y = fmaf(w0,v.y,a0.y);
            a0.z = fmaf(w0,v.z,a0.z); a0.w = fmaf(w0,v.w,a0.w);
            a1.x = fmaf(w1,v.x,a1.x); a1.y = fmaf(w1,v.y,a1.y);
            a1.z = fmaf(w1,v.z,a1.z); a1.w = fmaf(w1,v.w,a1.w);
        }
        int px0 = yg*W + x, px1 = (yg+48)*W + x;
        float4 b0 = B4[(size_t)pack*NPIX + px0];     // slice basis at output pixel
        float4 b1 = B4[(size_t)pack*NPIX + px1];
        float* dst = ones ? partVk : partV;
        dst[(size_t)pack*NPIX + px0] = a0.x*b0.x + a0.y*b0.y + a0.z*b0.z + a0.w*b0.w;
        dst[(size_t)pack*NPIX + px1] = a1.x*b1.x + a1.y*b1.y + a1.z*b1.z + a1.w*b1.w;
    } else {
        float h0 = 0.f, h1 = 0.f;
        #pragma unroll 4
        for (int yp = 0; yp < W; ++yp){
            float v = Hl3[r*97 + yp];
            h0 = fmaf(tw[yg - yp + 96],      v, h0);
            h1 = fmaf(tw[yg - yp + 96 + 48], v, h1);
        }
        float* dst = ones ? partVk : partV;
        dst[(size_t)pack*NPIX + yg*W + x]      = 3.f*h0;   // gaussian compat
        dst[(size_t)pack*NPIX + (yg+48)*W + x] = 3.f*h1;
    }
}

// ---- final: 5th update + argmax ----
__global__ __launch_bounds__(256) void k_F(const int* __restrict__ mask,
        const float* __restrict__ partV, const float* __restrict__ ksum,
        const float* __restrict__ qprev, float* __restrict__ out){
    int px = blockIdx.x*256 + threadIdx.x;
    float m = 0.f;
    #pragma unroll
    for (int p = 0; p < NP; ++p) m += partV[(size_t)p*NPIX + px];
    float duv = (mask[px]==0) ? LCLIP : -LCLIP;
    float delta = duv + ksum[px] - 2.f*(m - 13.f*qprev[px]);
    out[px] = (delta > 0.f) ? 1.f : 0.f;             // argmax; tie -> label 0
}

extern "C" void kernel_launch(void* const* d_in, const int* in_sizes, int n_in,
                              void* d_out, int out_size, void* d_ws, size_t ws_size,
                              hipStream_t stream){
    const float* img  = (const float*)d_in[0];
    const int*   mask = (const int*)d_in[1];
    float* out = (float*)d_out;
    float* ws  = (float*)d_ws;

    constexpr size_t TBL = (size_t)NPKB*NPIX*4;      // floats in a pack table
    float4* B4    = (float4*)ws;
    float4* H4T   = (float4*)(ws + TBL);
    float4* H4Tk  = (float4*)(ws + 2*TBL);
    float*  base  = ws + 3*TBL;
    float* H3T   = base;
    float* H3Tk  = H3T  + NPIX;
    float* partV = H3Tk + NPIX;                      // [13][NPIX]
    float* partVk= partV + (size_t)NP*NPIX;
    float* qA    = partVk + (size_t)NP*NPIX;
    float* qB    = qA + NPIX;
    float* ksum  = qB + NPIX;

    dim3 b(384);
    k_init<<<dim3(36), dim3(256), 0, stream>>>(img, B4);
    // iter 0: q0 (+ ones pipeline for ksum)
    k_H<0><<<dim3(12,2*NP), b, 0, stream>>>(mask, B4, partV, partVk, ksum, qA, qA, H4T, H3T, H4Tk, H3Tk);
    k_V   <<<dim3(12,2*NP), b, 0, stream>>>(B4, H4T, H4Tk, H3T, H3Tk, partV, partVk);
    // iter 1: recon q1, persist ksum
    k_H<1><<<dim3(12,NP), b, 0, stream>>>(mask, B4, partV, partVk, ksum, qA, qB, H4T, H3T, H4Tk, H3Tk);
    k_V   <<<dim3(12,NP), b, 0, stream>>>(B4, H4T, H4Tk, H3T, H3Tk, partV, partVk);
    // iters 2..4
    k_H<2><<<dim3(12,NP), b, 0, stream>>>(mask, B4, partV, partVk, ksum, qB, qA, H4T, H3T, H4Tk, H3Tk);
    k_V   <<<dim3(12,NP), b, 0, stream>>>(B4, H4T, H4Tk, H3T, H3Tk, partV, partVk);
    k_H<2><<<dim3(12,NP), b, 0, stream>>>(mask, B4, partV, partVk, ksum, qA, qB, H4T, H3T, H4Tk, H3Tk);
    k_V   <<<dim3(12,NP), b, 0, stream>>>(B4, H4T, H4Tk, H3T, H3Tk, partV, partVk);
    k_H<2><<<dim3(12,NP), b, 0, stream>>>(mask, B4, partV, partVk, ksum, qB, qA, H4T, H3T, H4Tk, H3Tk);
    k_V   <<<dim3(12,NP), b, 0, stream>>>(B4, H4T, H4Tk, H3T, H3Tk, partV, partVk);
    // iter 5: final update + argmax (qprev = q4 = qA)
    k_F<<<dim3(36), dim3(256), 0, stream>>>(mask, partV, ksum, qA, out);
}